// Round 1
// baseline (434.587 us; speedup 1.0000x reference)
//
#include <hip/hip_runtime.h>
#include <math.h>

// Problem constants
#define BB   8
#define SS   100
#define TT   1200        // S * DMAX
#define NM   80          // NMEL
#define DMC  128         // DM
#define KK   9
#define G3   384         // 3*DM
#define NROW (BB*TT)     // 9600

__device__ __forceinline__ float sigmoid_(float v) { return 1.f / (1.f + __expf(-v)); }
__device__ __forceinline__ float tanh_(float v) {
    float a = fabsf(v);
    float e = __expf(-2.f * a);
    float t = (1.f - e) / (1.f + e);
    return copysignf(t, v);
}

// ---------------------------------------------------------------------------
// Kernel S: per-batch prefix sum of durations -> starts[b][s]
// ---------------------------------------------------------------------------
__global__ void k_starts(const int* __restrict__ dur, int* __restrict__ starts) {
    __shared__ int buf[BB][128];
    int s = threadIdx.x;   // 0..127
    int b = threadIdx.y;   // 0..7
    int v = (s < SS) ? dur[b * SS + s] : 0;
    buf[b][s] = v;
    __syncthreads();
    for (int off = 1; off < 128; off <<= 1) {
        int t = (s >= off) ? buf[b][s - off] : 0;
        __syncthreads();
        buf[b][s] += t;
        __syncthreads();
    }
    if (s < SS) starts[b * SS + s] = buf[b][s] - v;  // exclusive scan
}

// ---------------------------------------------------------------------------
// Kernel T: transpose/pack w_hh into [dir][kc][g] float4 for coalesced loads
// ---------------------------------------------------------------------------
__global__ void k_wtrans(const float* __restrict__ wf, const float* __restrict__ wb,
                         float* __restrict__ wt) {
    int i = blockIdx.x * 256 + threadIdx.x;      // 0 .. 2*384*128-1
    if (i >= 2 * G3 * DMC) return;
    int e = i & 3;
    int r = i >> 2;          // (dir*32+kc)*384 + g
    int g = r % G3;
    int kcd = r / G3;
    int kc = kcd & 31;
    int dir = kcd >> 5;
    const float* w = dir ? wb : wf;
    wt[i] = w[g * DMC + kc * 4 + e];
}

// ---------------------------------------------------------------------------
// Kernel A: fused conv1 + BN/ReLU + conv2 + BN/ReLU, one (b,t) row per block
// ---------------------------------------------------------------------------
__global__ __launch_bounds__(256) void k_conv(
    const float* __restrict__ mel, const int* __restrict__ mel_len,
    const float* __restrict__ w1, const float* __restrict__ g1, const float* __restrict__ be1,
    const float* __restrict__ w2, const float* __restrict__ g2, const float* __restrict__ be2,
    float* __restrict__ xout) {
    int t = blockIdx.x, b = blockIdx.y;
    if (t >= mel_len[b]) return;   // row never consumed downstream

    __shared__ __align__(16) float melp[NM + 8];          // padded mel row
    __shared__ __align__(16) float y1p[DMC][NM + 8];      // padded conv1 out (44 KB)
    __shared__ __align__(16) float part[12][NM];          // conv2 partials

    int tid = threadIdx.x;
    const float inv_sqrt = 0.9999950000374997f;           // 1/sqrt(1+1e-5)

    if (tid < NM + 8) {
        float v = 0.f;
        if (tid >= 4 && tid < NM + 4) v = mel[(b * TT + t) * NM + tid - 4];
        melp[tid] = v;
    }
    __syncthreads();

    // ---- conv1: thread = (d, half-row of 40 m) ----
    {
        int d = tid >> 1, h = tid & 1, ms = h * 40;
        float wr[KK];
#pragma unroll
        for (int k = 0; k < KK; k++) wr[k] = w1[d * KK + k];
        float sc = g1[d] * inv_sqrt;
        float sb = be1[d];
        float win[48];
        const float4* mp4 = (const float4*)(melp + ms);
#pragma unroll
        for (int q = 0; q < 12; q++) {
            float4 v = mp4[q];
            win[q*4+0] = v.x; win[q*4+1] = v.y; win[q*4+2] = v.z; win[q*4+3] = v.w;
        }
        if (h == 0) { y1p[d][0]=0.f; y1p[d][1]=0.f; y1p[d][2]=0.f; y1p[d][3]=0.f; }
        else        { y1p[d][84]=0.f; y1p[d][85]=0.f; y1p[d][86]=0.f; y1p[d][87]=0.f; }
#pragma unroll
        for (int m = 0; m < 40; m++) {
            float acc = 0.f;
#pragma unroll
            for (int k = 0; k < KK; k++) acc = fmaf(wr[k], win[m + k], acc);
            y1p[d][4 + ms + m] = fmaxf(0.f, fmaf(acc, sc, sb));
        }
    }
    __syncthreads();

    // ---- conv2 partials: thread = (mg: 4 outputs, dp: d-stripe) ----
    if (tid < 240) {
        int mg = tid % 20, dp = tid / 20;   // dp 0..11
        float a0 = 0.f, a1 = 0.f, a2 = 0.f, a3 = 0.f;
        for (int d = dp; d < DMC; d += 12) {
            const float4* row4 = (const float4*)(&y1p[d][mg * 4]);
            float4 qa = row4[0], qb = row4[1], qc = row4[2];
            float wv[12] = {qa.x,qa.y,qa.z,qa.w, qb.x,qb.y,qb.z,qb.w, qc.x,qc.y,qc.z,qc.w};
            const float* w2d = w2 + d * KK;
#pragma unroll
            for (int k = 0; k < KK; k++) {
                float w = w2d[k];
                a0 = fmaf(w, wv[0 + k], a0);
                a1 = fmaf(w, wv[1 + k], a1);
                a2 = fmaf(w, wv[2 + k], a2);
                a3 = fmaf(w, wv[3 + k], a3);
            }
        }
        part[dp][mg*4+0] = a0; part[dp][mg*4+1] = a1;
        part[dp][mg*4+2] = a2; part[dp][mg*4+3] = a3;
    }
    __syncthreads();

    // ---- reduce partials + BN2/ReLU + store ----
    if (tid < NM) {
        float s = 0.f;
#pragma unroll
        for (int dp = 0; dp < 12; dp++) s += part[dp][tid];
        float v = fmaxf(0.f, fmaf(s, g2[0] * inv_sqrt, be2[0]));
        xout[(b * TT + t) * NM + tid] = v;
    }
}

// ---------------------------------------------------------------------------
// Kernel B: projection GEMM  xall[row][0:384]=f-gates, [384:768]=b-gates
// grid: (9600/32 row tiles, 8 col tiles of 96)
// ---------------------------------------------------------------------------
__global__ __launch_bounds__(256) void k_proj(
    const float* __restrict__ x,
    const float* __restrict__ wf, const float* __restrict__ wb,
    const float* __restrict__ bf, const float* __restrict__ bbv,
    float* __restrict__ xall) {
    __shared__ __align__(16) float xs[32 * 84];   // stride 84 breaks bank conflicts
    __shared__ __align__(16) float wsh[96 * 84];

    int tid = threadIdx.x;
    int row0 = blockIdx.x * 32;
    int cb = blockIdx.y;           // 0..7 ; 0..3 fwd, 4..7 bwd
    int g0 = cb * 96;              // global col
    const float* w    = (cb < 4) ? (wf + g0 * NM) : (wb + (g0 - G3) * NM);
    const float* bias = (cb < 4) ? (bf + g0)      : (bbv + (g0 - G3));

    for (int i = tid; i < 32 * NM; i += 256) {
        int r = i / NM, c = i - r * NM;
        xs[r * 84 + c] = x[(row0 + r) * NM + c];
    }
    for (int i = tid; i < 96 * NM; i += 256) {
        int r = i / NM, c = i - r * NM;
        wsh[r * 84 + c] = w[i];
    }
    __syncthreads();

    int cp = tid & 15, rp = tid >> 4;
    float4 acc[2][6];
#pragma unroll
    for (int rr = 0; rr < 2; rr++)
#pragma unroll
        for (int j = 0; j < 6; j++) acc[rr][j] = make_float4(0.f, 0.f, 0.f, 0.f);

    const float4* xs4 = (const float4*)xs;
    const float4* ws4 = (const float4*)wsh;
#pragma unroll
    for (int kc = 0; kc < 20; kc++) {
        float4 xa = xs4[rp * 21 + kc];
        float4 xbv = xs4[(rp + 16) * 21 + kc];
#pragma unroll
        for (int j = 0; j < 6; j++) {
            float4 wv = ws4[(cp + 16 * j) * 21 + kc];
            acc[0][j].x = fmaf(xa.x, wv.x, acc[0][j].x);
            acc[0][j].y = fmaf(xa.y, wv.y, acc[0][j].y);
            acc[0][j].z = fmaf(xa.z, wv.z, acc[0][j].z);
            acc[0][j].w = fmaf(xa.w, wv.w, acc[0][j].w);
            acc[1][j].x = fmaf(xbv.x, wv.x, acc[1][j].x);
            acc[1][j].y = fmaf(xbv.y, wv.y, acc[1][j].y);
            acc[1][j].z = fmaf(xbv.z, wv.z, acc[1][j].z);
            acc[1][j].w = fmaf(xbv.w, wv.w, acc[1][j].w);
        }
    }
#pragma unroll
    for (int rr = 0; rr < 2; rr++)
#pragma unroll
        for (int j = 0; j < 6; j++) {
            float4 a = acc[rr][j];
            float v = a.x + a.y + a.z + a.w + bias[cp + 16 * j];
            int row = row0 + rp + 16 * rr;
            xall[row * 768 + g0 + cp + 16 * j] = v;
        }
}

// ---------------------------------------------------------------------------
// Kernel C: per-segment GRU. grid (10 s-blocks, 8 b, 2 dir), 512 threads.
// Each wg owns 10 segments; 12 synchronized steps.
// ---------------------------------------------------------------------------
__global__ __launch_bounds__(512) void k_gru(
    const float* __restrict__ xall, const float* __restrict__ wt,
    const int* __restrict__ dur_all, const int* __restrict__ starts,
    const int* __restrict__ src_len,
    const float* __restrict__ bhf, const float* __restrict__ bhb,
    float* __restrict__ out) {
    int sblk = blockIdx.x;   // 0..9
    int b    = blockIdx.y;   // 0..7
    int dir  = blockIdx.z;   // 0 fwd, 1 bwd
    int s0 = sblk * 10;

    __shared__ __align__(16) float hs[10][DMC];
    __shared__ __align__(16) float gbuf[10][G3];
    __shared__ int sdur[10], sstart[10];

    int tid = threadIdx.x;
    if (tid < 10) {
        sdur[tid]   = dur_all[b * SS + s0 + tid];
        sstart[tid] = starts[b * SS + s0 + tid];
    }
    for (int i = tid; i < 10 * DMC; i += 512) ((float*)hs)[i] = 0.f;

    const float*  bh  = dir ? bhb : bhf;
    const float4* wt4 = (const float4*)(wt + dir * (G3 * DMC));
    int base = dir * G3;
    int gg = tid % 96, sp = tid / 96;   // sp 0..4 active (tid<480)
    __syncthreads();

    for (int i = 0; i < 12; i++) {
        // phase 1: gate matvec  gbuf[seg][g] = h[seg] . w_hh[g]
        if (sp < 5) {
            float4 acc[4][2];
#pragma unroll
            for (int j = 0; j < 4; j++)
#pragma unroll
                for (int q = 0; q < 2; q++) acc[j][q] = make_float4(0.f, 0.f, 0.f, 0.f);
            const float4* h0 = (const float4*)(&hs[2 * sp][0]);
            const float4* h1 = (const float4*)(&hs[2 * sp + 1][0]);
#pragma unroll
            for (int kc = 0; kc < 32; kc++) {
                float4 ha = h0[kc], hb2 = h1[kc];
#pragma unroll
                for (int j = 0; j < 4; j++) {
                    float4 wv = wt4[kc * G3 + gg + 96 * j];
                    acc[j][0].x = fmaf(wv.x, ha.x, acc[j][0].x);
                    acc[j][0].y = fmaf(wv.y, ha.y, acc[j][0].y);
                    acc[j][0].z = fmaf(wv.z, ha.z, acc[j][0].z);
                    acc[j][0].w = fmaf(wv.w, ha.w, acc[j][0].w);
                    acc[j][1].x = fmaf(wv.x, hb2.x, acc[j][1].x);
                    acc[j][1].y = fmaf(wv.y, hb2.y, acc[j][1].y);
                    acc[j][1].z = fmaf(wv.z, hb2.z, acc[j][1].z);
                    acc[j][1].w = fmaf(wv.w, hb2.w, acc[j][1].w);
                }
            }
#pragma unroll
            for (int j = 0; j < 4; j++)
#pragma unroll
                for (int q = 0; q < 2; q++) {
                    float4 a = acc[j][q];
                    gbuf[2 * sp + q][gg + 96 * j] = a.x + a.y + a.z + a.w;
                }
        }
        __syncthreads();

        // phase 2: elementwise GRU update + gather
        for (int u = tid; u < 10 * DMC; u += 512) {
            int seg = u >> 7, j = u & 127;
            int d = sdur[seg];
            if (i < d) {
                int t = dir ? (sstart[seg] + d - 1 - i) : (sstart[seg] + i);
                const float* xrow = xall + (b * TT + t) * 768 + base;
                float xr = xrow[j], xz = xrow[DMC + j], xn = xrow[2 * DMC + j];
                float hr = gbuf[seg][j]           + bh[j];
                float hz = gbuf[seg][DMC + j]     + bh[DMC + j];
                float hn = gbuf[seg][2 * DMC + j] + bh[2 * DMC + j];
                float hold = hs[seg][j];
                float r = sigmoid_(xr + hr);
                float z = sigmoid_(xz + hz);
                float n = tanh_(xn + r * hn);
                float hnew = (1.f - z) * n + z * hold;
                hs[seg][j] = hnew;
                if (i == d - 1) {
                    int s = s0 + seg;
                    float vout = (s < src_len[b]) ? hnew : 0.f;
                    out[(b * SS + s) * (2 * DMC) + dir * DMC + j] = vout;
                }
            }
        }
        __syncthreads();
    }
}

// ---------------------------------------------------------------------------
extern "C" void kernel_launch(void* const* d_in, const int* in_sizes, int n_in,
                              void* d_out, int out_size, void* d_ws, size_t ws_size,
                              hipStream_t stream) {
    const float* mel      = (const float*)d_in[0];
    const int*   durations= (const int*)  d_in[1];
    const int*   mel_len  = (const int*)  d_in[2];
    const int*   src_len  = (const int*)  d_in[3];
    const float* w1       = (const float*)d_in[4];
    const float* g1       = (const float*)d_in[5];
    const float* be1      = (const float*)d_in[6];
    const float* w2       = (const float*)d_in[7];
    const float* g2       = (const float*)d_in[8];
    const float* be2      = (const float*)d_in[9];
    const float* w_ih_f   = (const float*)d_in[10];
    const float* w_hh_f   = (const float*)d_in[11];
    const float* b_ih_f   = (const float*)d_in[12];
    const float* b_hh_f   = (const float*)d_in[13];
    const float* w_ih_b   = (const float*)d_in[14];
    const float* w_hh_b   = (const float*)d_in[15];
    const float* b_ih_b   = (const float*)d_in[16];
    const float* b_hh_b   = (const float*)d_in[17];
    float* out = (float*)d_out;

    // workspace layout (floats): x[9600*80] | xall[9600*768] | wt[2*384*128] | starts[800]
    float* x     = (float*)d_ws;
    float* xall  = x + NROW * NM;
    float* wt    = xall + NROW * 768;
    int*   starts= (int*)(wt + 2 * G3 * DMC);
    // total ~33 MB

    k_starts<<<1, dim3(128, 8), 0, stream>>>(durations, starts);
    k_wtrans<<<(2 * G3 * DMC + 255) / 256, 256, 0, stream>>>(w_hh_f, w_hh_b, wt);
    k_conv<<<dim3(TT, BB), 256, 0, stream>>>(mel, mel_len, w1, g1, be1, w2, g2, be2, x);
    k_proj<<<dim3(NROW / 32, 8), 256, 0, stream>>>(x, w_ih_f, w_ih_b, b_ih_f, b_ih_b, xall);
    k_gru<<<dim3(10, 8, 2), 512, 0, stream>>>(xall, wt, durations, starts, src_len,
                                              b_hh_f, b_hh_b, out);
}

// Round 2
// 239.250 us; speedup vs baseline: 1.8165x; 1.8165x over previous
//
#include <hip/hip_runtime.h>
#include <math.h>

// Problem constants
#define BB   8
#define SS   100
#define TT   1200        // S * DMAX
#define NM   80          // NMEL
#define DMC  128         // DM
#define KK   9
#define G3   384         // 3*DM
#define NROW (BB*TT)     // 9600

typedef __attribute__((ext_vector_type(8))) short short8;
typedef __attribute__((ext_vector_type(4))) float f32x4;

__device__ __forceinline__ float sigmoid_(float v) { return 1.f / (1.f + __expf(-v)); }
__device__ __forceinline__ float tanh_(float v) {
    float a = fabsf(v);
    float e = __expf(-2.f * a);
    float t = (1.f - e) / (1.f + e);
    return copysignf(t, v);
}
__device__ __forceinline__ unsigned short f2bf(float f) {   // RNE fp32->bf16
    unsigned int u = __float_as_uint(f);
    unsigned int r = (u + 0x7fffu + ((u >> 16) & 1u)) >> 16;
    return (unsigned short)r;
}

// ---------------------------------------------------------------------------
// Kernel S: per-batch prefix sum of durations -> starts[b][s]
// ---------------------------------------------------------------------------
__global__ void k_starts(const int* __restrict__ dur, int* __restrict__ starts) {
    __shared__ int buf[BB][128];
    int s = threadIdx.x;   // 0..127
    int b = threadIdx.y;   // 0..7
    int v = (s < SS) ? dur[b * SS + s] : 0;
    buf[b][s] = v;
    __syncthreads();
    for (int off = 1; off < 128; off <<= 1) {
        int t = (s >= off) ? buf[b][s - off] : 0;
        __syncthreads();
        buf[b][s] += t;
        __syncthreads();
    }
    if (s < SS) starts[b * SS + s] = buf[b][s] - v;  // exclusive scan
}

// ---------------------------------------------------------------------------
// Kernel W: pack w_hh into MFMA A-fragment order, split bf16 (hi + lo).
// A-frag (16x16x32 bf16): lane holds A[m=lane&15][k=(lane>>4)*8 + j], j=0..7
// index = (((dir*24+tau)*4+k32)*64 + lane)*8 + j
// ---------------------------------------------------------------------------
__global__ void k_wpack(const float* __restrict__ wf, const float* __restrict__ wb,
                        unsigned short* __restrict__ wph, unsigned short* __restrict__ wpl) {
    int idx = blockIdx.x * 256 + threadIdx.x;    // over 2*24*4*64 = 12288
    if (idx >= 2 * 24 * 4 * 64) return;
    int lane = idx & 63;
    int k32  = (idx >> 6) & 3;
    int tau  = (idx >> 8) % 24;
    int dir  = idx / (24 * 4 * 64);
    const float* w = dir ? wb : wf;
    int g = tau * 16 + (lane & 15);
    int kbase = k32 * 32 + (lane >> 4) * 8;
#pragma unroll
    for (int j = 0; j < 8; j++) {
        float v = w[g * DMC + kbase + j];
        unsigned short hi = f2bf(v);
        float hif = __uint_as_float(((unsigned)hi) << 16);
        unsigned short lo = f2bf(v - hif);
        wph[idx * 8 + j] = hi;
        wpl[idx * 8 + j] = lo;
    }
}

// ---------------------------------------------------------------------------
// Kernel A: fused conv1 + BN/ReLU + conv2 + BN/ReLU, one (b,t) row per block
// ---------------------------------------------------------------------------
__global__ __launch_bounds__(256) void k_conv(
    const float* __restrict__ mel, const int* __restrict__ mel_len,
    const float* __restrict__ w1, const float* __restrict__ g1, const float* __restrict__ be1,
    const float* __restrict__ w2, const float* __restrict__ g2, const float* __restrict__ be2,
    float* __restrict__ xout) {
    int t = blockIdx.x, b = blockIdx.y;
    if (t >= mel_len[b]) return;   // row never consumed downstream

    __shared__ __align__(16) float melp[NM + 8];          // padded mel row
    __shared__ __align__(16) float y1p[DMC][NM + 8];      // padded conv1 out (44 KB)
    __shared__ __align__(16) float part[12][NM];          // conv2 partials

    int tid = threadIdx.x;
    const float inv_sqrt = 0.9999950000374997f;           // 1/sqrt(1+1e-5)

    if (tid < NM + 8) {
        float v = 0.f;
        if (tid >= 4 && tid < NM + 4) v = mel[(b * TT + t) * NM + tid - 4];
        melp[tid] = v;
    }
    __syncthreads();

    // ---- conv1: thread = (d, half-row of 40 m) ----
    {
        int d = tid >> 1, h = tid & 1, ms = h * 40;
        float wr[KK];
#pragma unroll
        for (int k = 0; k < KK; k++) wr[k] = w1[d * KK + k];
        float sc = g1[d] * inv_sqrt;
        float sb = be1[d];
        float win[48];
        const float4* mp4 = (const float4*)(melp + ms);
#pragma unroll
        for (int q = 0; q < 12; q++) {
            float4 v = mp4[q];
            win[q*4+0] = v.x; win[q*4+1] = v.y; win[q*4+2] = v.z; win[q*4+3] = v.w;
        }
        if (h == 0) { y1p[d][0]=0.f; y1p[d][1]=0.f; y1p[d][2]=0.f; y1p[d][3]=0.f; }
        else        { y1p[d][84]=0.f; y1p[d][85]=0.f; y1p[d][86]=0.f; y1p[d][87]=0.f; }
#pragma unroll
        for (int m = 0; m < 40; m++) {
            float acc = 0.f;
#pragma unroll
            for (int k = 0; k < KK; k++) acc = fmaf(wr[k], win[m + k], acc);
            y1p[d][4 + ms + m] = fmaxf(0.f, fmaf(acc, sc, sb));
        }
    }
    __syncthreads();

    // ---- conv2 partials: thread = (mg: 4 outputs, dp: d-stripe) ----
    if (tid < 240) {
        int mg = tid % 20, dp = tid / 20;   // dp 0..11
        float a0 = 0.f, a1 = 0.f, a2 = 0.f, a3 = 0.f;
        for (int d = dp; d < DMC; d += 12) {
            const float4* row4 = (const float4*)(&y1p[d][mg * 4]);
            float4 qa = row4[0], qb = row4[1], qc = row4[2];
            float wv[12] = {qa.x,qa.y,qa.z,qa.w, qb.x,qb.y,qb.z,qb.w, qc.x,qc.y,qc.z,qc.w};
            const float* w2d = w2 + d * KK;
#pragma unroll
            for (int k = 0; k < KK; k++) {
                float w = w2d[k];
                a0 = fmaf(w, wv[0 + k], a0);
                a1 = fmaf(w, wv[1 + k], a1);
                a2 = fmaf(w, wv[2 + k], a2);
                a3 = fmaf(w, wv[3 + k], a3);
            }
        }
        part[dp][mg*4+0] = a0; part[dp][mg*4+1] = a1;
        part[dp][mg*4+2] = a2; part[dp][mg*4+3] = a3;
    }
    __syncthreads();

    // ---- reduce partials + BN2/ReLU + store ----
    if (tid < NM) {
        float s = 0.f;
#pragma unroll
        for (int dp = 0; dp < 12; dp++) s += part[dp][tid];
        float v = fmaxf(0.f, fmaf(s, g2[0] * inv_sqrt, be2[0]));
        xout[(b * TT + t) * NM + tid] = v;
    }
}

// ---------------------------------------------------------------------------
// Kernel B: projection GEMM  xall[row][0:384]=f-gates, [384:768]=b-gates
// ---------------------------------------------------------------------------
__global__ __launch_bounds__(256) void k_proj(
    const float* __restrict__ x,
    const float* __restrict__ wf, const float* __restrict__ wb,
    const float* __restrict__ bf, const float* __restrict__ bbv,
    float* __restrict__ xall) {
    __shared__ __align__(16) float xs[32 * 84];
    __shared__ __align__(16) float wsh[96 * 84];

    int tid = threadIdx.x;
    int row0 = blockIdx.x * 32;
    int cb = blockIdx.y;           // 0..7 ; 0..3 fwd, 4..7 bwd
    int g0 = cb * 96;              // global col
    const float* w    = (cb < 4) ? (wf + g0 * NM) : (wb + (g0 - G3) * NM);
    const float* bias = (cb < 4) ? (bf + g0)      : (bbv + (g0 - G3));

    for (int i = tid; i < 32 * NM; i += 256) {
        int r = i / NM, c = i - r * NM;
        xs[r * 84 + c] = x[(row0 + r) * NM + c];
    }
    for (int i = tid; i < 96 * NM; i += 256) {
        int r = i / NM, c = i - r * NM;
        wsh[r * 84 + c] = w[i];
    }
    __syncthreads();

    int cp = tid & 15, rp = tid >> 4;
    float4 acc[2][6];
#pragma unroll
    for (int rr = 0; rr < 2; rr++)
#pragma unroll
        for (int j = 0; j < 6; j++) acc[rr][j] = make_float4(0.f, 0.f, 0.f, 0.f);

    const float4* xs4 = (const float4*)xs;
    const float4* ws4 = (const float4*)wsh;
#pragma unroll
    for (int kc = 0; kc < 20; kc++) {
        float4 xa = xs4[rp * 21 + kc];
        float4 xbv = xs4[(rp + 16) * 21 + kc];
#pragma unroll
        for (int j = 0; j < 6; j++) {
            float4 wv = ws4[(cp + 16 * j) * 21 + kc];
            acc[0][j].x = fmaf(xa.x, wv.x, acc[0][j].x);
            acc[0][j].y = fmaf(xa.y, wv.y, acc[0][j].y);
            acc[0][j].z = fmaf(xa.z, wv.z, acc[0][j].z);
            acc[0][j].w = fmaf(xa.w, wv.w, acc[0][j].w);
            acc[1][j].x = fmaf(xbv.x, wv.x, acc[1][j].x);
            acc[1][j].y = fmaf(xbv.y, wv.y, acc[1][j].y);
            acc[1][j].z = fmaf(xbv.z, wv.z, acc[1][j].z);
            acc[1][j].w = fmaf(xbv.w, wv.w, acc[1][j].w);
        }
    }
#pragma unroll
    for (int rr = 0; rr < 2; rr++)
#pragma unroll
        for (int j = 0; j < 6; j++) {
            float4 a = acc[rr][j];
            float v = a.x + a.y + a.z + a.w + bias[cp + 16 * j];
            int row = row0 + rp + 16 * rr;
            xall[row * 768 + g0 + cp + 16 * j] = v;
        }
}

// ---------------------------------------------------------------------------
// Kernel C: per-segment GRU via MFMA, split-bf16 for fp32-class accuracy.
// grid (7 s-blocks of 16 segs, 8 b, 2 dir), 384 threads (6 waves).
// Wave w owns gate tiles tau = 4w..4w+3 (24 tiles of 16 gates = 384 gates).
// A-frags (w_hh hi/lo) live in VGPRs across all 12 iterations.
// ---------------------------------------------------------------------------
__global__ __launch_bounds__(384) void k_gru(
    const float* __restrict__ xall,
    const unsigned short* __restrict__ wph, const unsigned short* __restrict__ wpl,
    const int* __restrict__ dur_all, const int* __restrict__ starts,
    const int* __restrict__ src_len,
    const float* __restrict__ bhf, const float* __restrict__ bhb,
    float* __restrict__ out) {
    int sblk = blockIdx.x;   // 0..6
    int b    = blockIdx.y;   // 0..7
    int dir  = blockIdx.z;   // 0 fwd, 1 bwd
    int s0 = sblk * 16;

    __shared__ __align__(16) float hs[16][DMC];                 // fp32 h (exact)
    __shared__ __align__(16) unsigned short hbh[4 * 64 * 8];    // B-frag layout, hi
    __shared__ __align__(16) unsigned short hbl[4 * 64 * 8];    // B-frag layout, lo
    __shared__ __align__(16) float gbuf[16][388];               // gates [seg][g]
    __shared__ int sdur[16], sstart[16];

    int tid  = threadIdx.x;
    int wave = tid >> 6, lane = tid & 63;

    if (tid < 16) {
        int s = s0 + tid;
        sdur[tid]   = (s < SS) ? dur_all[b * SS + s] : 0;
        sstart[tid] = (s < SS) ? starts[b * SS + s]  : 0;
    }
    for (int i = tid; i < 16 * DMC; i += 384) ((float*)hs)[i] = 0.f;
    for (int i = tid; i < 2048; i += 384) { hbh[i] = 0; hbl[i] = 0; }

    // ---- load A-fragments once (registers, persist all 12 iterations) ----
    short8 Ah[4][4], Al[4][4];
    const short8* wph8 = (const short8*)wph;
    const short8* wpl8 = (const short8*)wpl;
#pragma unroll
    for (int tt = 0; tt < 4; tt++)
#pragma unroll
        for (int k32 = 0; k32 < 4; k32++) {
            int tau = wave * 4 + tt;
            int idx = ((dir * 24 + tau) * 4 + k32) * 64 + lane;
            Ah[tt][k32] = wph8[idx];
            Al[tt][k32] = wpl8[idx];
        }

    const float* bh = dir ? bhb : bhf;
    int xbase = dir * G3;
    int seg_c = lane & 15, quad = lane >> 4;
    __syncthreads();

    for (int i = 0; i < 12; i++) {
        // ---- phase 1: D[g][seg] = h . w_hh   (3-term split-bf16 MFMA) ----
        f32x4 acc[4];
#pragma unroll
        for (int tt = 0; tt < 4; tt++) acc[tt] = (f32x4){0.f, 0.f, 0.f, 0.f};
#pragma unroll
        for (int k32 = 0; k32 < 4; k32++) {
            short8 Bh = ((const short8*)hbh)[k32 * 64 + lane];
            short8 Bl = ((const short8*)hbl)[k32 * 64 + lane];
#pragma unroll
            for (int tt = 0; tt < 4; tt++) {
                acc[tt] = __builtin_amdgcn_mfma_f32_16x16x32_bf16(Ah[tt][k32], Bh, acc[tt], 0, 0, 0);
                acc[tt] = __builtin_amdgcn_mfma_f32_16x16x32_bf16(Ah[tt][k32], Bl, acc[tt], 0, 0, 0);
                acc[tt] = __builtin_amdgcn_mfma_f32_16x16x32_bf16(Al[tt][k32], Bh, acc[tt], 0, 0, 0);
            }
        }
#pragma unroll
        for (int tt = 0; tt < 4; tt++) {
            int g = (wave * 4 + tt) * 16 + quad * 4;    // row = quad*4+reg (m89)
            *(f32x4*)&gbuf[seg_c][g] = acc[tt];
        }
        __syncthreads();

        // ---- phase 2: elementwise GRU update + output gather ----
        for (int u = tid; u < 16 * DMC; u += 384) {
            int seg = u >> 7, j = u & 127;
            int d = sdur[seg];
            if (i < d) {
                int t = dir ? (sstart[seg] + d - 1 - i) : (sstart[seg] + i);
                const float* xrow = xall + (b * TT + t) * 768 + xbase;
                float xr = xrow[j], xz = xrow[DMC + j], xn = xrow[2 * DMC + j];
                float hr = gbuf[seg][j]           + bh[j];
                float hz = gbuf[seg][DMC + j]     + bh[DMC + j];
                float hn = gbuf[seg][2 * DMC + j] + bh[2 * DMC + j];
                float hold = hs[seg][j];
                float r = sigmoid_(xr + hr);
                float z = sigmoid_(xz + hz);
                float n = tanh_(xn + r * hn);
                float hnew = (1.f - z) * n + z * hold;
                hs[seg][j] = hnew;
                // split-bf16 copies in B-frag layout: k = j
                unsigned short hi = f2bf(hnew);
                float hif = __uint_as_float(((unsigned)hi) << 16);
                unsigned short lo = f2bf(hnew - hif);
                int addr = ((j >> 5) * 64 + ((j & 31) >> 3) * 16 + seg) * 8 + (j & 7);
                hbh[addr] = hi;
                hbl[addr] = lo;
                if (i == d - 1) {
                    int s = s0 + seg;
                    float vout = (s < src_len[b]) ? hnew : 0.f;
                    out[(b * SS + s) * (2 * DMC) + dir * DMC + j] = vout;
                }
            }
        }
        __syncthreads();
    }
}

// ---------------------------------------------------------------------------
extern "C" void kernel_launch(void* const* d_in, const int* in_sizes, int n_in,
                              void* d_out, int out_size, void* d_ws, size_t ws_size,
                              hipStream_t stream) {
    const float* mel      = (const float*)d_in[0];
    const int*   durations= (const int*)  d_in[1];
    const int*   mel_len  = (const int*)  d_in[2];
    const int*   src_len  = (const int*)  d_in[3];
    const float* w1       = (const float*)d_in[4];
    const float* g1       = (const float*)d_in[5];
    const float* be1      = (const float*)d_in[6];
    const float* w2       = (const float*)d_in[7];
    const float* g2       = (const float*)d_in[8];
    const float* be2      = (const float*)d_in[9];
    const float* w_ih_f   = (const float*)d_in[10];
    const float* w_hh_f   = (const float*)d_in[11];
    const float* b_ih_f   = (const float*)d_in[12];
    const float* b_hh_f   = (const float*)d_in[13];
    const float* w_ih_b   = (const float*)d_in[14];
    const float* w_hh_b   = (const float*)d_in[15];
    const float* b_ih_b   = (const float*)d_in[16];
    const float* b_hh_b   = (const float*)d_in[17];
    float* out = (float*)d_out;

    // workspace layout: x[9600*80] f | xall[9600*768] f | wph/wpl[2*24*4*64*8] u16 | starts[800] i32
    float* x     = (float*)d_ws;
    float* xall  = x + NROW * NM;
    unsigned short* wph = (unsigned short*)(xall + NROW * 768);
    unsigned short* wpl = wph + 2 * 24 * 4 * 64 * 8;
    int*   starts= (int*)(wpl + 2 * 24 * 4 * 64 * 8);

    k_starts<<<1, dim3(128, 8), 0, stream>>>(durations, starts);
    k_wpack<<<48, 256, 0, stream>>>(w_hh_f, w_hh_b, wph, wpl);
    k_conv<<<dim3(TT, BB), 256, 0, stream>>>(mel, mel_len, w1, g1, be1, w2, g2, be2, x);
    k_proj<<<dim3(NROW / 32, 8), 256, 0, stream>>>(x, w_ih_f, w_ih_b, b_ih_f, b_ih_b, xall);
    k_gru<<<dim3(7, 8, 2), 384, 0, stream>>>(xall, wph, wpl, durations, starts, src_len,
                                             b_hh_f, b_hh_b, out);
}